// Round 3
// baseline (44.178 us; speedup 1.0000x reference)
//
#include <hip/hip_runtime.h>
#include <math.h>

// Problem constants: B=16, N=128, h=256, goal_dim=64, obs_dim=128, local=64, skills=16

typedef float f32x4 __attribute__((ext_vector_type(4)));
typedef short s16x8 __attribute__((ext_vector_type(8)));

// ---- workspace layout (float offsets) ----
#define WQT_OFF   0        // f32 [64][256]
#define WKT_OFF   16384    // f32 [128][256]
#define WVT_OFF   49152    // f32 [128][256]
#define WOBF_OFF  81920    // bf16 [256][256] (row-major, = original Wo layout)
#define QBF_OFF   114688   // bf16 [2048][256] row-major
#define KBF_OFF   376832   // bf16 [2048][256] row-major (b*128+m row)
#define VTBF_OFF  638976   // bf16 [16][256][128]  (V transposed per batch)
// end 901120 floats = 3.6 MB

// ---- output layout (float offsets, tuple return order) ----
#define LOGIT_OFF 0        // [16][128][16]
#define MASK_OFF  32768    // [16][128][128]
#define ATTN_OFF  294912   // [16][128][128]
#define OUT_OFF   557056   // [16][128][256]

static __device__ __forceinline__ unsigned short f2bf(float x) {
  unsigned int u = __float_as_uint(x);
  u = (u + 0x7fffu + ((u >> 16) & 1u)) >> 16;   // RNE
  return (unsigned short)u;
}

__global__ __launch_bounds__(256) void transpose_k(
    const float* __restrict__ Wq, const float* __restrict__ Wk,
    const float* __restrict__ Wv, const float* __restrict__ Wo,
    float* __restrict__ ws) {
  int idx = blockIdx.x * 256 + threadIdx.x;
  if (idx < 16384) {                      // WqT[i][o], I=64, O=256
    int i = idx >> 8, o = idx & 255;
    ws[WQT_OFF + idx] = Wq[o * 64 + i];
  } else if (idx < 49152) {               // WkT, I=128, O=256
    int j = idx - 16384; int i = j >> 8, o = j & 255;
    ws[WKT_OFF + j] = Wk[o * 128 + i];
  } else if (idx < 81920) {               // WvT
    int j = idx - 49152; int i = j >> 8, o = j & 255;
    ws[WVT_OFF + j] = Wv[o * 128 + i];
  } else if (idx < 147456) {              // Wo -> bf16 (row-major, no transpose)
    int j = idx - 81920;
    ((unsigned short*)(ws + WOBF_OFF))[j] = f2bf(Wo[j]);
  }
}

// blocks 0..127: Q (16 rows each).  blocks 128..383: K+V (8 rows each).
// f32 compute (verified), bf16 stores in MFMA-friendly layouts.
__global__ __launch_bounds__(256) void proj_k(
    const float* __restrict__ goals, const float* __restrict__ agents,
    const float* __restrict__ bq, const float* __restrict__ bk,
    const float* __restrict__ bv, float* __restrict__ ws) {
  const float* WqT = ws + WQT_OFF;
  const float* WkT = ws + WKT_OFF;
  const float* WvT = ws + WVT_OFF;
  unsigned short* qbf  = (unsigned short*)(ws + QBF_OFF);
  unsigned short* kbf  = (unsigned short*)(ws + KBF_OFF);
  unsigned short* vtbf = (unsigned short*)(ws + VTBF_OFF);
  int t = threadIdx.x;
  int bid = blockIdx.x;
  if (bid < 128) {
    __shared__ __align__(16) float xs[16][64];
    int row0 = bid * 16;
    for (int i = t; i < 1024; i += 256) xs[i >> 6][i & 63] = goals[row0 * 64 + i];
    __syncthreads();
    float acc[16];
#pragma unroll
    for (int r = 0; r < 16; r++) acc[r] = 0.f;
    for (int d = 0; d < 64; d += 4) {
      float w0 = WqT[(d + 0) * 256 + t];
      float w1 = WqT[(d + 1) * 256 + t];
      float w2 = WqT[(d + 2) * 256 + t];
      float w3 = WqT[(d + 3) * 256 + t];
#pragma unroll
      for (int r = 0; r < 16; r++) {
        float4 x4 = *(const float4*)&xs[r][d];
        acc[r] = fmaf(w0, x4.x, acc[r]);
        acc[r] = fmaf(w1, x4.y, acc[r]);
        acc[r] = fmaf(w2, x4.z, acc[r]);
        acc[r] = fmaf(w3, x4.w, acc[r]);
      }
    }
    float bb = bq[t];
#pragma unroll
    for (int r = 0; r < 16; r++) qbf[(size_t)(row0 + r) * 256 + t] = f2bf(acc[r] + bb);
  } else {
    __shared__ __align__(16) float xs2[8][128];
    int row0 = (bid - 128) * 8;
    for (int i = t; i < 1024; i += 256) xs2[i >> 7][i & 127] = agents[row0 * 128 + i];
    __syncthreads();
    float accK[8], accV[8];
#pragma unroll
    for (int r = 0; r < 8; r++) { accK[r] = 0.f; accV[r] = 0.f; }
    for (int d = 0; d < 128; d += 4) {
      float k0 = WkT[(d + 0) * 256 + t], k1 = WkT[(d + 1) * 256 + t];
      float k2 = WkT[(d + 2) * 256 + t], k3 = WkT[(d + 3) * 256 + t];
      float v0 = WvT[(d + 0) * 256 + t], v1 = WvT[(d + 1) * 256 + t];
      float v2 = WvT[(d + 2) * 256 + t], v3 = WvT[(d + 3) * 256 + t];
#pragma unroll
      for (int r = 0; r < 8; r++) {
        float4 x4 = *(const float4*)&xs2[r][d];
        accK[r] = fmaf(k0, x4.x, accK[r]); accK[r] = fmaf(k1, x4.y, accK[r]);
        accK[r] = fmaf(k2, x4.z, accK[r]); accK[r] = fmaf(k3, x4.w, accK[r]);
        accV[r] = fmaf(v0, x4.x, accV[r]); accV[r] = fmaf(v1, x4.y, accV[r]);
        accV[r] = fmaf(v2, x4.z, accV[r]); accV[r] = fmaf(v3, x4.w, accV[r]);
      }
    }
    float bbk = bk[t], bbv = bv[t];
    int b = row0 >> 7;
#pragma unroll
    for (int r = 0; r < 8; r++) {
      kbf[(size_t)(row0 + r) * 256 + t] = f2bf(accK[r] + bbk);          // K row-major
      vtbf[(size_t)(b * 256 + t) * 128 + (row0 & 127) + r] = f2bf(accV[r] + bbv);  // V^T
    }
  }
}

// one block per (batch b, 8-row n tile): 256 blocks x 512 threads (8 waves).
// Computes a 16-row MFMA logits tile (2x redundant), softmax for its own 8 rows,
// PV + out-proj MFMA with the other 8 A-rows zeroed, skill head in f32.
__global__ __launch_bounds__(512) void attn_k(
    const float* __restrict__ goals, const float* __restrict__ agents_local,
    const float* __restrict__ u1, const float* __restrict__ u2,
    const float* __restrict__ bo, const float* __restrict__ Wsm,
    const float* __restrict__ bs, const float* __restrict__ ws,
    float* __restrict__ out) {
  const unsigned short* Qbf  = (const unsigned short*)(ws + QBF_OFF);
  const unsigned short* Kbf  = (const unsigned short*)(ws + KBF_OFF);
  const unsigned short* VTbf = (const unsigned short*)(ws + VTBF_OFF);
  const unsigned short* Wobf = (const unsigned short*)(ws + WOBF_OFF);
  float* o_logit = out + LOGIT_OFF;
  float* o_mask  = out + MASK_OFF;
  float* o_attn  = out + ATTN_OFF;
  float* o_out   = out + OUT_OFF;

  int bid = blockIdx.x;
  int b  = bid & 15;
  int n0 = (bid >> 4) << 3;
  int rtile = n0 & 0x70;      // 16-row MFMA window
  int soff  = n0 & 8;         // our half within the window
  int t = threadIdx.x;
  int w = t >> 6, l = t & 63, lr = l & 15, lc = l >> 4;

  __shared__ __align__(16) float S[16 * 140];            // logits f32
  __shared__ __align__(16) unsigned short Wb[16 * 136];  // attn*mask bf16 (A of PV)
  __shared__ __align__(16) unsigned short Ib[16 * 264];  // info bf16 (A of out-proj)
  __shared__ __align__(16) float outb[8 * 260];          // out rows f32 (skill input)
  __shared__ float redmax[8][2], redsum[8][2];

  // ---- phase L: logits via MFMA.  D[row][m] = sum_h Q[row][h] K[m][h] ----
  {
    const s16x8* ap = (const s16x8*)(Qbf + (size_t)(b * 128 + rtile + lr) * 256);
    const s16x8* bp = (const s16x8*)(Kbf + (size_t)(b * 128 + 16 * w + lr) * 256);
    f32x4 acc = {0.f, 0.f, 0.f, 0.f};
#pragma unroll
    for (int kk = 0; kk < 8; kk++)
      acc = __builtin_amdgcn_mfma_f32_16x16x32_bf16(ap[kk * 4 + lc], bp[kk * 4 + lc], acc, 0, 0, 0);
#pragma unroll
    for (int q = 0; q < 4; q++) S[(4 * lc + q) * 140 + 16 * w + lr] = acc[q] * 0.0625f;
    // zero the other-half rows of Wb (A rows we don't own -> zero rows in PV)
    unsigned int* wz = (unsigned int*)(Wb + (soff ^ 8) * 136);
    for (int i = t; i < 544; i += 512) wz[i] = 0u;
  }
  __syncthreads();

  // ---- phase S: gumbel-sigmoid mask + scores + softmax (2 rows/thread, f32) ----
  {
    int m = t & 127, rg = t >> 7, half = (t >> 6) & 1;
    int rl0 = 2 * rg;
    float sc[2], mk[2], ev[2];
#pragma unroll
    for (int i = 0; i < 2; i++) {
      int rloc = rl0 + i;
      float lg = S[(soff + rloc) * 140 + m];
      int row = b * 128 + n0 + rloc;
      float uu1 = u1[row * 128 + m];
      float uu2 = u2[row * 128 + m];
      float g1 = -__logf(-__logf(uu1 + 1e-20f) + 1e-20f);
      float g2 = -__logf(-__logf(uu2 + 1e-20f) + 1e-20f);
      float z = lg + g1 - g2;                       // TAU = 1
      float mkv = 1.0f / (1.0f + __expf(-z));
      mk[i] = mkv;
      o_mask[row * 128 + m] = mkv;
      sc[i] = lg + __logf(mkv + 1e-8f);
    }
    float v0 = sc[0], v1 = sc[1];
#pragma unroll
    for (int off = 32; off >= 1; off >>= 1) {
      v0 = fmaxf(v0, __shfl_xor(v0, off));
      v1 = fmaxf(v1, __shfl_xor(v1, off));
    }
    if ((t & 63) == 0) { redmax[rl0][half] = v0; redmax[rl0 + 1][half] = v1; }
    __syncthreads();
#pragma unroll
    for (int i = 0; i < 2; i++) {
      float rmax = fmaxf(redmax[rl0 + i][0], redmax[rl0 + i][1]);
      ev[i] = __expf(sc[i] - rmax);
    }
    float s0 = ev[0], s1 = ev[1];
#pragma unroll
    for (int off = 32; off >= 1; off >>= 1) {
      s0 += __shfl_xor(s0, off);
      s1 += __shfl_xor(s1, off);
    }
    if ((t & 63) == 0) { redsum[rl0][half] = s0; redsum[rl0 + 1][half] = s1; }
    __syncthreads();
#pragma unroll
    for (int i = 0; i < 2; i++) {
      int rloc = rl0 + i;
      float rsum = redsum[rloc][0] + redsum[rloc][1];
      float attn = ev[i] / rsum;
      int row = b * 128 + n0 + rloc;
      o_attn[row * 128 + m] = attn;
      Wb[(soff + rloc) * 136 + m] = f2bf(attn * mk[i]);
    }
  }
  __syncthreads();

  // ---- phase PV: info[row][h] = sum_m W[row][m] V[m][h] ----
  {
#pragma unroll
    for (int hs = 0; hs < 2; hs++) {
      int h0 = (w + 8 * hs) * 16;
      f32x4 acc = {0.f, 0.f, 0.f, 0.f};
#pragma unroll
      for (int kk = 0; kk < 4; kk++) {
        s16x8 a = *(const s16x8*)(Wb + lr * 136 + kk * 32 + lc * 8);
        s16x8 bf = *(const s16x8*)(VTbf + (size_t)(b * 256 + h0 + lr) * 128 + kk * 32 + lc * 8);
        acc = __builtin_amdgcn_mfma_f32_16x16x32_bf16(a, bf, acc, 0, 0, 0);
      }
#pragma unroll
      for (int q = 0; q < 4; q++) Ib[(4 * lc + q) * 264 + h0 + lr] = f2bf(acc[q]);
    }
  }
  __syncthreads();

  // ---- phase O: out[row][g] = sum_h info[row][h] Wo[g][h] + bo[g] ----
  {
#pragma unroll
    for (int gs = 0; gs < 2; gs++) {
      int g0 = (w + 8 * gs) * 16;
      f32x4 acc = {0.f, 0.f, 0.f, 0.f};
#pragma unroll
      for (int kk = 0; kk < 8; kk++) {
        s16x8 a = *(const s16x8*)(Ib + lr * 264 + kk * 32 + lc * 8);
        s16x8 bf = *(const s16x8*)(Wobf + (size_t)(g0 + lr) * 256 + kk * 32 + lc * 8);
        acc = __builtin_amdgcn_mfma_f32_16x16x32_bf16(a, bf, acc, 0, 0, 0);
      }
      float bov = bo[g0 + lr];
      if ((lc >> 1) == (soff >> 3)) {                 // rows we own
#pragma unroll
        for (int q = 0; q < 4; q++) {
          int rloc = (4 * lc + q) & 7;
          float val = acc[q] + bov;
          o_out[(size_t)(b * 128 + n0 + rloc) * 256 + g0 + lr] = val;
          outb[rloc * 260 + g0 + lr] = val;
        }
      }
    }
  }
  __syncthreads();

  // ---- phase K: skill logits, f32. t = (rloc<<6) | (s<<2) | p ----
  {
    int rloc = t >> 6, s = (t >> 2) & 15, p = t & 3;
    int row = b * 128 + n0 + rloc;
    const float4* Ws4 = (const float4*)(Wsm + s * 384);
    const float4* lp4 = (const float4*)(agents_local + (size_t)row * 64);
    const float4* gp4 = (const float4*)(goals + (size_t)row * 64);
    float acc = 0.f;
#pragma unroll
    for (int i = 0; i < 24; i++) {
      int cc = p * 96 + i * 4;
      float4 c4;
      if (cc < 64)       c4 = lp4[cc >> 2];
      else if (cc < 128) c4 = gp4[(cc - 64) >> 2];
      else               c4 = *(const float4*)&outb[rloc * 260 + (cc - 128)];
      float4 w4 = Ws4[cc >> 2];
      acc = fmaf(w4.x, c4.x, fmaf(w4.y, c4.y, fmaf(w4.z, c4.z, fmaf(w4.w, c4.w, acc))));
    }
    acc += __shfl_xor(acc, 1);
    acc += __shfl_xor(acc, 2);
    if (p == 0) o_logit[row * 16 + s] = acc + bs[s];
  }
}

extern "C" void kernel_launch(void* const* d_in, const int* in_sizes, int n_in,
                              void* d_out, int out_size, void* d_ws, size_t ws_size,
                              hipStream_t stream) {
  const float* goals        = (const float*)d_in[0];
  const float* agents       = (const float*)d_in[1];
  const float* agents_local = (const float*)d_in[2];
  const float* u1           = (const float*)d_in[3];
  const float* u2           = (const float*)d_in[4];
  const float* Wq = (const float*)d_in[5];
  const float* bq = (const float*)d_in[6];
  const float* Wk = (const float*)d_in[7];
  const float* bk = (const float*)d_in[8];
  const float* Wv = (const float*)d_in[9];
  const float* bv = (const float*)d_in[10];
  const float* Wo = (const float*)d_in[11];
  const float* bo = (const float*)d_in[12];
  const float* Wsm = (const float*)d_in[13];
  const float* bs  = (const float*)d_in[14];
  float* out = (float*)d_out;
  float* ws  = (float*)d_ws;

  transpose_k<<<576, 256, 0, stream>>>(Wq, Wk, Wv, Wo, ws);
  proj_k<<<384, 256, 0, stream>>>(goals, agents, bq, bk, bv, ws);
  attn_k<<<256, 512, 0, stream>>>(goals, agents_local, u1, u2, bo, Wsm, bs, ws, out);
}